// Round 3
// baseline (107.506 us; speedup 1.0000x reference)
//
#include <hip/hip_runtime.h>
#include <math.h>

#define NDIM 1024
#define BDIM 128
#define TS 32
#define NT (NDIM / TS)                 // 32
#define NTILES (NT * (NT + 1) / 2)     // 528 upper-tri tiles
#define NC 32                          // spread copies for atomic accumulator
#define CNT_OFF (NC * BDIM)            // counter offset (floats); 16384 B, 128B-aligned

// Single fused kernel. One block per upper-tri 32x32 tile:
//   contribution(b) = q_bi * RS_i + r_bi * (sum_j W_ij * v_bj)
// with q=1-v, r=2v-1, RS_i = masked row sum. 1 MAC per W element.
//
// Cross-tile reduction fused via contention-spread atomic accumulator
// acc[NC][BDIM] in workspace (zeroed by hipMemsetAsync, same stream, so
// graph replay re-zeros it every iteration). Block t adds its 128 values
// into slot (t & 31) (~16 blocks/slot -> negligible serialization; global
// atomics are device-coherent across XCDs). Last block (atomic counter)
// folds the 32x128 accumulator and writes out[128]. No deadlock path:
// blocks never wait on each other.
__global__ __launch_bounds__(256) void potts_fused(
    const float* __restrict__ V,      // [128][1024]
    const float* __restrict__ W,      // [1024][1024]
    float* __restrict__ ws,           // acc[NC][BDIM]; counter @ float CNT_OFF
    float* __restrict__ out)          // [128]
{
    const int t = blockIdx.x;
    // closed-form upper-tri tile index (verified rounds 0-1: same absmax)
    const int u = NTILES - 1 - t;
    int kk = (int)(0.5f * (sqrtf((float)(8 * u + 1)) - 1.0f));
    if (kk * (kk + 1) / 2 > u) --kk;
    if ((kk + 1) * (kk + 2) / 2 <= u) ++kk;
    const int ti = NT - 1 - kk;
    const int tj = NT - 1 - (u - kk * (kk + 1) / 2);
    const int I0 = ti * TS, J0 = tj * TS;
    const bool diag = (ti == tj);

    __shared__ float4 vj4[BDIM][8];     // V[b][J0+4*j4..+4] at column j4^(b&7)
    __shared__ float4 vi4[BDIM][8];     // V[b][I0+4*j4..+4] at column j4^(b&7)
    __shared__ float rs[TS];            // masked row sums
    __shared__ float red[4][BDIM];
    __shared__ int lastflag;

    const int tid = threadIdx.x;
    const int w = tid >> 6;
    const int l = tid & 63;
    const int l7 = l & 7;

    // ---- masked W row sums via one float4/thread + 8-lane shfl reduce
    {
        const int r = tid >> 3, c4 = (tid & 7) * 4;
        float4 w4 = *(const float4*)(W + (size_t)(I0 + r) * NDIM + (J0 + c4));
        if (diag) {                      // triu: keep j >= i
            if (c4 + 0 < r) w4.x = 0.0f;
            if (c4 + 1 < r) w4.y = 0.0f;
            if (c4 + 2 < r) w4.z = 0.0f;
            if (c4 + 3 < r) w4.w = 0.0f;
        }
        float rsum = (w4.x + w4.y) + (w4.z + w4.w);
        rsum += __shfl_xor(rsum, 1);
        rsum += __shfl_xor(rsum, 2);
        rsum += __shfl_xor(rsum, 4);
        if ((tid & 7) == 0) rs[r] = rsum;
    }

    // ---- stage V slices, natural orientation, swizzled float4 columns
#pragma unroll
    for (int it = 0; it < 4; ++it) {
        const int fid = tid + 256 * it;       // 0..1023
        const int b = fid >> 3, j4 = fid & 7;
        const int g = j4 ^ (b & 7);
        vj4[b][g] = *(const float4*)(V + (size_t)b * NDIM + (J0 + 4 * j4));
        vi4[b][g] = *(const float4*)(V + (size_t)b * NDIM + (I0 + 4 * j4));
    }
    __syncthreads();

    // ---- per-lane vj registers (b128 reads, swizzle-matched)
    float vj0[TS], vj1[TS];
#pragma unroll
    for (int j4 = 0; j4 < 8; ++j4) {
        const int g = j4 ^ l7;
        const float4 a = vj4[l][g];
        vj0[4*j4+0] = a.x; vj0[4*j4+1] = a.y;
        vj0[4*j4+2] = a.z; vj0[4*j4+3] = a.w;
        const float4 c = vj4[l + 64][g];
        vj1[4*j4+0] = c.x; vj1[4*j4+1] = c.y;
        vj1[4*j4+2] = c.z; vj1[4*j4+3] = c.w;
    }
    // ---- per-lane vi registers: this wave's 8 tile rows
    float vi0[8], vi1[8];
    {
        const int ga = (2 * w) ^ l7, gb = (2 * w + 1) ^ l7;
        const float4 p  = vi4[l][ga],      q  = vi4[l][gb];
        const float4 p1 = vi4[l + 64][ga], q1 = vi4[l + 64][gb];
        vi0[0]=p.x;  vi0[1]=p.y;  vi0[2]=p.z;  vi0[3]=p.w;
        vi0[4]=q.x;  vi0[5]=q.y;  vi0[6]=q.z;  vi0[7]=q.w;
        vi1[0]=p1.x; vi1[1]=p1.y; vi1[2]=p1.z; vi1[3]=p1.w;
        vi1[4]=q1.x; vi1[5]=q1.y; vi1[6]=q1.z; vi1[7]=q1.w;
    }

    float acc0 = 0.0f, acc1 = 0.0f;
#pragma unroll
    for (int k = 0; k < 8; ++k) {
        const int i = 8 * w + k;
        const float* __restrict__ wrow = W + (size_t)(I0 + i) * NDIM + J0;
        float za0 = 0.f, zb0 = 0.f, za1 = 0.f, zb1 = 0.f;
#pragma unroll
        for (int j4 = 0; j4 < 8; j4 += 2) {
            float4 wa = *(const float4*)(wrow + 4 * j4);       // L1-hot broadcast
            float4 wb = *(const float4*)(wrow + 4 * j4 + 4);
            if (diag) {                  // triu mask, per-k uniform
                if (4*j4 + 0 < i) wa.x = 0.0f;
                if (4*j4 + 1 < i) wa.y = 0.0f;
                if (4*j4 + 2 < i) wa.z = 0.0f;
                if (4*j4 + 3 < i) wa.w = 0.0f;
                if (4*j4 + 4 < i) wb.x = 0.0f;
                if (4*j4 + 5 < i) wb.y = 0.0f;
                if (4*j4 + 6 < i) wb.z = 0.0f;
                if (4*j4 + 7 < i) wb.w = 0.0f;
            }
            za0 = fmaf(wa.x, vj0[4*j4+0], za0);
            za0 = fmaf(wa.y, vj0[4*j4+1], za0);
            za0 = fmaf(wa.z, vj0[4*j4+2], za0);
            za0 = fmaf(wa.w, vj0[4*j4+3], za0);
            za1 = fmaf(wa.x, vj1[4*j4+0], za1);
            za1 = fmaf(wa.y, vj1[4*j4+1], za1);
            za1 = fmaf(wa.z, vj1[4*j4+2], za1);
            za1 = fmaf(wa.w, vj1[4*j4+3], za1);
            zb0 = fmaf(wb.x, vj0[4*j4+4], zb0);
            zb0 = fmaf(wb.y, vj0[4*j4+5], zb0);
            zb0 = fmaf(wb.z, vj0[4*j4+6], zb0);
            zb0 = fmaf(wb.w, vj0[4*j4+7], zb0);
            zb1 = fmaf(wb.x, vj1[4*j4+4], zb1);
            zb1 = fmaf(wb.y, vj1[4*j4+5], zb1);
            zb1 = fmaf(wb.z, vj1[4*j4+6], zb1);
            zb1 = fmaf(wb.w, vj1[4*j4+7], zb1);
        }
        const float y0 = vi0[k], y1 = vi1[k];
        const float rsk = rs[i];
        acc0 = fmaf(1.0f - y0, rsk, acc0);
        acc0 = fmaf(2.0f * y0 - 1.0f, za0 + zb0, acc0);
        acc1 = fmaf(1.0f - y1, rsk, acc1);
        acc1 = fmaf(2.0f * y1 - 1.0f, za1 + zb1, acc1);
    }

    // ---- block reduce (4 waves -> 128 values)
    red[w][l] = acc0;
    red[w][l + 64] = acc1;
    __syncthreads();

    // ---- spread atomic accumulate into ws slot (t & 31)
    float* slot = ws + (size_t)(t & (NC - 1)) * BDIM;
    if (tid < BDIM) {
        const float v4 = (red[0][tid] + red[1][tid]) + (red[2][tid] + red[3][tid]);
        atomicAdd(slot + tid, v4);       // device-scope global atomic
    }

    // ---- last-block election + fold
    __threadfence();                     // release our adds before the ticket
    __syncthreads();
    if (tid == 0) {
        unsigned int* cnt = (unsigned int*)(ws + CNT_OFF);
        const unsigned int old =
            __hip_atomic_fetch_add(cnt, 1u, __ATOMIC_ACQ_REL,
                                   __HIP_MEMORY_SCOPE_AGENT);
        lastflag = (old == NTILES - 1) ? 1 : 0;
    }
    __syncthreads();
    if (lastflag && tid < BDIM) {
        float s = 0.0f;
#pragma unroll
        for (int c = 0; c < NC; ++c) {
            s += __hip_atomic_load(ws + (size_t)c * BDIM + tid,
                                   __ATOMIC_RELAXED, __HIP_MEMORY_SCOPE_AGENT);
        }
        out[tid] = s;
    }
}

extern "C" void kernel_launch(void* const* d_in, const int* in_sizes, int n_in,
                              void* d_out, int out_size, void* d_ws, size_t ws_size,
                              hipStream_t stream) {
    const float* V = (const float*)d_in[0];
    const float* W = (const float*)d_in[1];
    float* out = (float*)d_out;
    float* ws = (float*)d_ws;            // 16384 B acc + counter = 16448 B

    hipMemsetAsync(d_ws, 0, (CNT_OFF + 16) * sizeof(float), stream);
    potts_fused<<<dim3(NTILES), dim3(256), 0, stream>>>(V, W, ws, out);
}

// Round 4
// 77.462 us; speedup vs baseline: 1.3879x; 1.3879x over previous
//
#include <hip/hip_runtime.h>
#include <math.h>

#define NDIM 1024
#define BDIM 128
#define TS 32
#define NT (NDIM / TS)                 // 32
#define NTILES (NT * (NT + 1) / 2)     // 528 upper-tri tiles

// Single kernel, one block per upper-tri 32x32 tile:
//   contribution(b) = q_bi * RS_i + r_bi * (sum_j W_ij * v_bj)
// with q=1-v, r=2v-1, RS_i = masked row sum. 1 MAC per W element.
//
// Cross-tile reduction: each block block-reduces to 128 values and does
// plain relaxed atomicAdd into out[128] (pre-zeroed by hipMemsetAsync).
// NO fences, NO election counter, NO agent-scope acquire — round 3 showed
// per-block release/acquire cache-maintenance serializes to ~53us. Plain
// device-scope atomicAdd is coherent across XCDs (guide G12/m20) and
// fire-and-forget: blocks exit immediately after their 128 adds.
__global__ __launch_bounds__(256) void potts_fused(
    const float* __restrict__ V,      // [128][1024]
    const float* __restrict__ W,      // [1024][1024]
    float* __restrict__ out)          // [128], zeroed before launch
{
    const int t = blockIdx.x;
    // closed-form upper-tri tile index (verified rounds 0-3: same absmax)
    const int u = NTILES - 1 - t;
    int kk = (int)(0.5f * (sqrtf((float)(8 * u + 1)) - 1.0f));
    if (kk * (kk + 1) / 2 > u) --kk;
    if ((kk + 1) * (kk + 2) / 2 <= u) ++kk;
    const int ti = NT - 1 - kk;
    const int tj = NT - 1 - (u - kk * (kk + 1) / 2);
    const int I0 = ti * TS, J0 = tj * TS;
    const bool diag = (ti == tj);

    __shared__ float4 vj4[BDIM][8];     // V[b][J0+4*j4..+4] at column j4^(b&7)
    __shared__ float4 vi4[BDIM][8];     // V[b][I0+4*j4..+4] at column j4^(b&7)
    __shared__ float rs[TS];            // masked row sums
    __shared__ float red[4][BDIM];

    const int tid = threadIdx.x;
    const int w = tid >> 6;
    const int l = tid & 63;
    const int l7 = l & 7;

    // ---- masked W row sums via one float4/thread + 8-lane shfl reduce
    {
        const int r = tid >> 3, c4 = (tid & 7) * 4;
        float4 w4 = *(const float4*)(W + (size_t)(I0 + r) * NDIM + (J0 + c4));
        if (diag) {                      // triu: keep j >= i
            if (c4 + 0 < r) w4.x = 0.0f;
            if (c4 + 1 < r) w4.y = 0.0f;
            if (c4 + 2 < r) w4.z = 0.0f;
            if (c4 + 3 < r) w4.w = 0.0f;
        }
        float rsum = (w4.x + w4.y) + (w4.z + w4.w);
        rsum += __shfl_xor(rsum, 1);
        rsum += __shfl_xor(rsum, 2);
        rsum += __shfl_xor(rsum, 4);
        if ((tid & 7) == 0) rs[r] = rsum;
    }

    // ---- stage V slices, natural orientation, swizzled float4 columns
#pragma unroll
    for (int it = 0; it < 4; ++it) {
        const int fid = tid + 256 * it;       // 0..1023
        const int b = fid >> 3, j4 = fid & 7;
        const int g = j4 ^ (b & 7);
        vj4[b][g] = *(const float4*)(V + (size_t)b * NDIM + (J0 + 4 * j4));
        vi4[b][g] = *(const float4*)(V + (size_t)b * NDIM + (I0 + 4 * j4));
    }
    __syncthreads();

    // ---- per-lane vj registers (b128 reads, swizzle-matched)
    float vj0[TS], vj1[TS];
#pragma unroll
    for (int j4 = 0; j4 < 8; ++j4) {
        const int g = j4 ^ l7;
        const float4 a = vj4[l][g];
        vj0[4*j4+0] = a.x; vj0[4*j4+1] = a.y;
        vj0[4*j4+2] = a.z; vj0[4*j4+3] = a.w;
        const float4 c = vj4[l + 64][g];
        vj1[4*j4+0] = c.x; vj1[4*j4+1] = c.y;
        vj1[4*j4+2] = c.z; vj1[4*j4+3] = c.w;
    }
    // ---- per-lane vi registers: this wave's 8 tile rows
    float vi0[8], vi1[8];
    {
        const int ga = (2 * w) ^ l7, gb = (2 * w + 1) ^ l7;
        const float4 p  = vi4[l][ga],      q  = vi4[l][gb];
        const float4 p1 = vi4[l + 64][ga], q1 = vi4[l + 64][gb];
        vi0[0]=p.x;  vi0[1]=p.y;  vi0[2]=p.z;  vi0[3]=p.w;
        vi0[4]=q.x;  vi0[5]=q.y;  vi0[6]=q.z;  vi0[7]=q.w;
        vi1[0]=p1.x; vi1[1]=p1.y; vi1[2]=p1.z; vi1[3]=p1.w;
        vi1[4]=q1.x; vi1[5]=q1.y; vi1[6]=q1.z; vi1[7]=q1.w;
    }

    float acc0 = 0.0f, acc1 = 0.0f;
#pragma unroll
    for (int k = 0; k < 8; ++k) {
        const int i = 8 * w + k;
        const float* __restrict__ wrow = W + (size_t)(I0 + i) * NDIM + J0;
        float za0 = 0.f, zb0 = 0.f, za1 = 0.f, zb1 = 0.f;
#pragma unroll
        for (int j4 = 0; j4 < 8; j4 += 2) {
            float4 wa = *(const float4*)(wrow + 4 * j4);       // L1-hot broadcast
            float4 wb = *(const float4*)(wrow + 4 * j4 + 4);
            if (diag) {                  // triu mask, per-k uniform
                if (4*j4 + 0 < i) wa.x = 0.0f;
                if (4*j4 + 1 < i) wa.y = 0.0f;
                if (4*j4 + 2 < i) wa.z = 0.0f;
                if (4*j4 + 3 < i) wa.w = 0.0f;
                if (4*j4 + 4 < i) wb.x = 0.0f;
                if (4*j4 + 5 < i) wb.y = 0.0f;
                if (4*j4 + 6 < i) wb.z = 0.0f;
                if (4*j4 + 7 < i) wb.w = 0.0f;
            }
            za0 = fmaf(wa.x, vj0[4*j4+0], za0);
            za0 = fmaf(wa.y, vj0[4*j4+1], za0);
            za0 = fmaf(wa.z, vj0[4*j4+2], za0);
            za0 = fmaf(wa.w, vj0[4*j4+3], za0);
            za1 = fmaf(wa.x, vj1[4*j4+0], za1);
            za1 = fmaf(wa.y, vj1[4*j4+1], za1);
            za1 = fmaf(wa.z, vj1[4*j4+2], za1);
            za1 = fmaf(wa.w, vj1[4*j4+3], za1);
            zb0 = fmaf(wb.x, vj0[4*j4+4], zb0);
            zb0 = fmaf(wb.y, vj0[4*j4+5], zb0);
            zb0 = fmaf(wb.z, vj0[4*j4+6], zb0);
            zb0 = fmaf(wb.w, vj0[4*j4+7], zb0);
            zb1 = fmaf(wb.x, vj1[4*j4+4], zb1);
            zb1 = fmaf(wb.y, vj1[4*j4+5], zb1);
            zb1 = fmaf(wb.z, vj1[4*j4+6], zb1);
            zb1 = fmaf(wb.w, vj1[4*j4+7], zb1);
        }
        const float y0 = vi0[k], y1 = vi1[k];
        const float rsk = rs[i];
        acc0 = fmaf(1.0f - y0, rsk, acc0);
        acc0 = fmaf(2.0f * y0 - 1.0f, za0 + zb0, acc0);
        acc1 = fmaf(1.0f - y1, rsk, acc1);
        acc1 = fmaf(2.0f * y1 - 1.0f, za1 + zb1, acc1);
    }

    // ---- block reduce (4 waves -> 128 values), then fire-and-forget atomics
    red[w][l] = acc0;
    red[w][l + 64] = acc1;
    __syncthreads();
    if (tid < BDIM) {
        const float v4 = (red[0][tid] + red[1][tid]) + (red[2][tid] + red[3][tid]);
        atomicAdd(&out[tid], v4);        // relaxed device-scope, no fence
    }
}

extern "C" void kernel_launch(void* const* d_in, const int* in_sizes, int n_in,
                              void* d_out, int out_size, void* d_ws, size_t ws_size,
                              hipStream_t stream) {
    const float* V = (const float*)d_in[0];
    const float* W = (const float*)d_in[1];
    float* out = (float*)d_out;
    (void)d_ws; (void)ws_size;

    hipMemsetAsync(d_out, 0, BDIM * sizeof(float), stream);
    potts_fused<<<dim3(NTILES), dim3(256), 0, stream>>>(V, W, out);
}